// Round 1
// baseline (4084.032 us; speedup 1.0000x reference)
//
#include <hip/hip_runtime.h>

// Fused 3-layer tanh RNN (B=131072, T=6, V=31) + linear + tanh + softmax.
// One thread per batch element; weights read via wave-uniform (SGPR) loads;
// all state in VGPRs; single kernel, no workspace traffic.

#define VD 31
#define TD 6
#define LD 3

__device__ __forceinline__ float fast_tanh(float x) {
    // tanh(x) = (e^{2x}-1)/(e^{2x}+1); clamp to keep e^{2x} finite.
    x = fminf(fmaxf(x, -15.0f), 15.0f);
    float e = __expf(2.0f * x);
    return (e - 1.0f) * __builtin_amdgcn_rcpf(e + 1.0f);
}

__device__ __forceinline__ void layer_step(
    const float* __restrict__ wih, const float* __restrict__ whh,
    const float* __restrict__ bih, const float* __restrict__ bhh,
    const float (&x)[VD], const float (&hin)[VD], float (&hout)[VD])
{
#pragma unroll
    for (int j = 0; j < VD; ++j) {
        float acc = bih[j] + bhh[j];
        const float* wi = wih + j * VD;
        const float* wh = whh + j * VD;
#pragma unroll
        for (int k = 0; k < VD; ++k) acc = fmaf(wi[k], x[k], acc);
#pragma unroll
        for (int k = 0; k < VD; ++k) acc = fmaf(wh[k], hin[k], acc);
        hout[j] = fast_tanh(acc);
    }
}

__global__ __launch_bounds__(256, 2) void rnn_fused(
    const float* __restrict__ inp,   // [B, T, V]
    const float* __restrict__ h0,    // [L, B, V]
    const float* __restrict__ Wih,   // [L, V, V]
    const float* __restrict__ Whh,   // [L, V, V]
    const float* __restrict__ bih,   // [L, V]
    const float* __restrict__ bhh,   // [L, V]
    const float* __restrict__ Wlin,  // [V, V]
    const float* __restrict__ blin,  // [V]
    float* __restrict__ out,         // [B, V]
    int B)
{
    const int b = blockIdx.x * blockDim.x + threadIdx.x;
    if (b >= B) return;

    float h1[VD], h2[VD], h3[VD];
    {
        const float* p0 = h0 + (size_t)b * VD;
        const float* p1 = h0 + ((size_t)B + b) * VD;
        const float* p2 = h0 + ((size_t)2 * B + b) * VD;
#pragma unroll
        for (int j = 0; j < VD; ++j) { h1[j] = p0[j]; h2[j] = p1[j]; h3[j] = p2[j]; }
    }

    const float* xb = inp + (size_t)b * TD * VD;

    for (int t = 0; t < TD; ++t) {
        float xt[VD];
#pragma unroll
        for (int k = 0; k < VD; ++k) xt[k] = xb[t * VD + k];

        float tmp[VD];
        // layer 1: x_t, h1 -> h1
        layer_step(Wih + 0 * VD * VD, Whh + 0 * VD * VD, bih + 0 * VD, bhh + 0 * VD,
                   xt, h1, tmp);
#pragma unroll
        for (int j = 0; j < VD; ++j) h1[j] = tmp[j];
        // layer 2: h1, h2 -> h2
        layer_step(Wih + 1 * VD * VD, Whh + 1 * VD * VD, bih + 1 * VD, bhh + 1 * VD,
                   h1, h2, tmp);
#pragma unroll
        for (int j = 0; j < VD; ++j) h2[j] = tmp[j];
        // layer 3: h2, h3 -> h3
        layer_step(Wih + 2 * VD * VD, Whh + 2 * VD * VD, bih + 2 * VD, bhh + 2 * VD,
                   h2, h3, tmp);
#pragma unroll
        for (int j = 0; j < VD; ++j) h3[j] = tmp[j];
    }

    // final linear + tanh (only last timestep feeds the output)
    float logits[VD];
#pragma unroll
    for (int j = 0; j < VD; ++j) {
        float acc = blin[j];
        const float* wl = Wlin + j * VD;
#pragma unroll
        for (int k = 0; k < VD; ++k) acc = fmaf(wl[k], h3[k], acc);
        logits[j] = fast_tanh(acc);
    }

    // softmax over the 31 logits
    float m = logits[0];
#pragma unroll
    for (int j = 1; j < VD; ++j) m = fmaxf(m, logits[j]);
    float e[VD];
    float s = 0.0f;
#pragma unroll
    for (int j = 0; j < VD; ++j) { e[j] = __expf(logits[j] - m); s += e[j]; }
    const float inv = __builtin_amdgcn_rcpf(s);
    float* ob = out + (size_t)b * VD;
#pragma unroll
    for (int j = 0; j < VD; ++j) ob[j] = e[j] * inv;
}

extern "C" void kernel_launch(void* const* d_in, const int* in_sizes, int n_in,
                              void* d_out, int out_size, void* d_ws, size_t ws_size,
                              hipStream_t stream) {
    const float* inp  = (const float*)d_in[0];
    const float* h0   = (const float*)d_in[1];
    const float* Wih  = (const float*)d_in[2];
    const float* Whh  = (const float*)d_in[3];
    const float* bih  = (const float*)d_in[4];
    const float* bhh  = (const float*)d_in[5];
    const float* Wlin = (const float*)d_in[6];
    const float* blin = (const float*)d_in[7];
    float* out = (float*)d_out;

    const int B = in_sizes[0] / (TD * VD);
    const int block = 256;
    const int grid = (B + block - 1) / block;
    rnn_fused<<<grid, block, 0, stream>>>(inp, h0, Wih, Whh, bih, bhh, Wlin, blin, out, B);
}

// Round 2
// 1222.264 us; speedup vs baseline: 3.3414x; 3.3414x over previous
//
#include <hip/hip_runtime.h>

// Fused 3-layer tanh RNN (B=131072, T=6, V=31) + linear + tanh + softmax.
// One thread per batch element; weights are wave-uniform (SGPR loads);
// all state in VGPRs.
//
// R2 change: __launch_bounds__(256,1). R1 used (256,2) and the compiler
// capped VGPRs at 128 while ~155 floats are live -> spill to scratch
// (WRITE_SIZE 62 MB vs 16 MB ideal, 30x VALU bloat, 4 ms). With a 512-reg
// cap the allocator can hold all state; 129-256 VGPRs still gives
// 2 waves/SIMD (m69), so occupancy is unchanged but spills vanish.

#define VD 31
#define TD 6
#define LD 3

__device__ __forceinline__ float fast_tanh(float x) {
    // tanh(x) = (e^{2x}-1)/(e^{2x}+1); clamp to keep e^{2x} finite.
    x = fminf(fmaxf(x, -15.0f), 15.0f);
    float e = __expf(2.0f * x);
    return (e - 1.0f) * __builtin_amdgcn_rcpf(e + 1.0f);
}

__device__ __forceinline__ void layer_step(
    const float* __restrict__ wih, const float* __restrict__ whh,
    const float* __restrict__ bih, const float* __restrict__ bhh,
    const float (&x)[VD], const float (&hin)[VD], float (&hout)[VD])
{
#pragma unroll
    for (int j = 0; j < VD; ++j) {
        // two independent fma chains halve the dependent-latency depth
        float acc_i = bih[j];
        float acc_h = bhh[j];
        const float* wi = wih + j * VD;
        const float* wh = whh + j * VD;
#pragma unroll
        for (int k = 0; k < VD; ++k) acc_i = fmaf(wi[k], x[k], acc_i);
#pragma unroll
        for (int k = 0; k < VD; ++k) acc_h = fmaf(wh[k], hin[k], acc_h);
        hout[j] = fast_tanh(acc_i + acc_h);
    }
}

__global__ __launch_bounds__(256, 1) void rnn_fused(
    const float* __restrict__ inp,   // [B, T, V]
    const float* __restrict__ h0,    // [L, B, V]
    const float* __restrict__ Wih,   // [L, V, V]
    const float* __restrict__ Whh,   // [L, V, V]
    const float* __restrict__ bih,   // [L, V]
    const float* __restrict__ bhh,   // [L, V]
    const float* __restrict__ Wlin,  // [V, V]
    const float* __restrict__ blin,  // [V]
    float* __restrict__ out,         // [B, V]
    int B)
{
    const int b = blockIdx.x * blockDim.x + threadIdx.x;
    if (b >= B) return;

    float h1[VD], h2[VD], h3[VD];
    {
        const float* p0 = h0 + (size_t)b * VD;
        const float* p1 = h0 + ((size_t)B + b) * VD;
        const float* p2 = h0 + ((size_t)2 * B + b) * VD;
#pragma unroll
        for (int j = 0; j < VD; ++j) { h1[j] = p0[j]; h2[j] = p1[j]; h3[j] = p2[j]; }
    }

    const float* xb = inp + (size_t)b * TD * VD;

    for (int t = 0; t < TD; ++t) {
        float xt[VD];
#pragma unroll
        for (int k = 0; k < VD; ++k) xt[k] = xb[t * VD + k];

        float tmp[VD];
        // layer 1: x_t, h1 -> h1
        layer_step(Wih + 0 * VD * VD, Whh + 0 * VD * VD, bih + 0 * VD, bhh + 0 * VD,
                   xt, h1, tmp);
#pragma unroll
        for (int j = 0; j < VD; ++j) h1[j] = tmp[j];
        // layer 2: h1, h2 -> h2
        layer_step(Wih + 1 * VD * VD, Whh + 1 * VD * VD, bih + 1 * VD, bhh + 1 * VD,
                   h1, h2, tmp);
#pragma unroll
        for (int j = 0; j < VD; ++j) h2[j] = tmp[j];
        // layer 3: h2, h3 -> h3
        layer_step(Wih + 2 * VD * VD, Whh + 2 * VD * VD, bih + 2 * VD, bhh + 2 * VD,
                   h2, h3, tmp);
#pragma unroll
        for (int j = 0; j < VD; ++j) h3[j] = tmp[j];
    }

    // final linear + tanh (only last timestep feeds the output)
    float logits[VD];
#pragma unroll
    for (int j = 0; j < VD; ++j) {
        float acc = blin[j];
        const float* wl = Wlin + j * VD;
#pragma unroll
        for (int k = 0; k < VD; ++k) acc = fmaf(wl[k], h3[k], acc);
        logits[j] = fast_tanh(acc);
    }

    // softmax over the 31 logits
    float m = logits[0];
#pragma unroll
    for (int j = 1; j < VD; ++j) m = fmaxf(m, logits[j]);
    float e[VD];
    float s = 0.0f;
#pragma unroll
    for (int j = 0; j < VD; ++j) { e[j] = __expf(logits[j] - m); s += e[j]; }
    const float inv = __builtin_amdgcn_rcpf(s);
    float* ob = out + (size_t)b * VD;
#pragma unroll
    for (int j = 0; j < VD; ++j) ob[j] = e[j] * inv;
}

extern "C" void kernel_launch(void* const* d_in, const int* in_sizes, int n_in,
                              void* d_out, int out_size, void* d_ws, size_t ws_size,
                              hipStream_t stream) {
    const float* inp  = (const float*)d_in[0];
    const float* h0   = (const float*)d_in[1];
    const float* Wih  = (const float*)d_in[2];
    const float* Whh  = (const float*)d_in[3];
    const float* bih  = (const float*)d_in[4];
    const float* bhh  = (const float*)d_in[5];
    const float* Wlin = (const float*)d_in[6];
    const float* blin = (const float*)d_in[7];
    float* out = (float*)d_out;

    const int B = in_sizes[0] / (TD * VD);
    const int block = 256;
    const int grid = (B + block - 1) / block;
    rnn_fused<<<grid, block, 0, stream>>>(inp, h0, Wih, Whh, bih, bhh, Wlin, blin, out, B);
}